// Round 2
// baseline (2075.304 us; speedup 1.0000x reference)
//
#include <hip/hip_runtime.h>
#include <math.h>

typedef unsigned short u16;
typedef __attribute__((ext_vector_type(8))) short short8;
typedef __attribute__((ext_vector_type(4))) float floatx4;

#define Hh 16
#define Mm 1024
#define Dd 512
#define Oo 512
#define Nn 16384

__device__ __forceinline__ float b2f(u16 u) { return __uint_as_float(((unsigned)u) << 16); }
__device__ __forceinline__ u16 f2b(float f) {
    unsigned v = __float_as_uint(f);
    v += 0x7fffu + ((v >> 16) & 1u);
    return (u16)(v >> 16);
}
__device__ __forceinline__ short8 cvt8(const float* p) {
    float4 a = *(const float4*)p, b = *(const float4*)(p + 4);
    u16 o[8];
    o[0] = f2b(a.x); o[1] = f2b(a.y); o[2] = f2b(a.z); o[3] = f2b(a.w);
    o[4] = f2b(b.x); o[5] = f2b(b.y); o[6] = f2b(b.z); o[7] = f2b(b.w);
    return *(short8*)o;
}

// ---------------------------------------------------------------------------
// Generic GEMM-BT: C[h][m][n] = sum_k A[h][m][k] * B[h][n][k] (+ bias[h][n])
// ---------------------------------------------------------------------------
__global__ __launch_bounds__(256) void gemm_bt(
    const void* __restrict__ A, const void* __restrict__ B, const float* __restrict__ bias,
    void* __restrict__ C, int K, int lda, int ldb, int ldc,
    long sA, long sB, long sBias, long sC, int aF32, int bF32, int outBf)
{
    __shared__ u16 At[64][72];
    __shared__ u16 Bt[64][72];
    const int tid = threadIdx.x, lane = tid & 63, wid = tid >> 6;
    const int m0 = blockIdx.y * 64, n0 = blockIdx.x * 64;
    const int h = blockIdx.z;
    const int wm = wid >> 1, wn = wid & 1;
    const int rl = lane & 15, rq = (lane >> 4) * 4, gl8 = (lane >> 4) * 8;

    floatx4 zero4 = {0.f, 0.f, 0.f, 0.f};
    floatx4 acc[2][2];
    acc[0][0] = zero4; acc[0][1] = zero4; acc[1][0] = zero4; acc[1][1] = zero4;

    for (int k0 = 0; k0 < K; k0 += 64) {
#pragma unroll
        for (int i = 0; i < 2; i++) {
            int c = tid + i * 256;
            int r = c >> 3, cc = (c & 7) * 8;
            long aoff = (long)h * sA + (long)(m0 + r) * lda + k0 + cc;
            long boff = (long)h * sB + (long)(n0 + r) * ldb + k0 + cc;
            *(short8*)&At[r][cc] = aF32 ? cvt8((const float*)A + aoff)
                                        : *(const short8*)((const u16*)A + aoff);
            *(short8*)&Bt[r][cc] = bF32 ? cvt8((const float*)B + boff)
                                        : *(const short8*)((const u16*)B + boff);
        }
        __syncthreads();
#pragma unroll
        for (int ks = 0; ks < 2; ks++) {
            short8 a0 = *(const short8*)&At[wm * 32 + rl][ks * 32 + gl8];
            short8 a1 = *(const short8*)&At[wm * 32 + 16 + rl][ks * 32 + gl8];
            short8 b0 = *(const short8*)&Bt[wn * 32 + rl][ks * 32 + gl8];
            short8 b1 = *(const short8*)&Bt[wn * 32 + 16 + rl][ks * 32 + gl8];
            acc[0][0] = __builtin_amdgcn_mfma_f32_16x16x32_bf16(a0, b0, acc[0][0], 0, 0, 0);
            acc[0][1] = __builtin_amdgcn_mfma_f32_16x16x32_bf16(a0, b1, acc[0][1], 0, 0, 0);
            acc[1][0] = __builtin_amdgcn_mfma_f32_16x16x32_bf16(a1, b0, acc[1][0], 0, 0, 0);
            acc[1][1] = __builtin_amdgcn_mfma_f32_16x16x32_bf16(a1, b1, acc[1][1], 0, 0, 0);
        }
        __syncthreads();
    }

#pragma unroll
    for (int i = 0; i < 2; i++)
#pragma unroll
        for (int j = 0; j < 2; j++) {
            int col = n0 + wn * 32 + j * 16 + rl;
            float bb = bias ? bias[(long)h * sBias + col] : 0.f;
#pragma unroll
            for (int r = 0; r < 4; r++) {
                int row = m0 + wm * 32 + i * 16 + rq + r;
                long idx = (long)h * sC + (long)row * ldc + col;
                float v = acc[i][j][r] + bb;
                if (outBf) ((u16*)C)[idx] = f2b(v);
                else       ((float*)C)[idx] = v;
            }
        }
}

// ---------------------------------------------------------------------------
// Row softmax: rows of 512 fp32 logits -> bf16 probabilities. One wave/row.
// ---------------------------------------------------------------------------
__global__ __launch_bounds__(256) void softmax_rows(const float* __restrict__ L, u16* __restrict__ Kout)
{
    const int tid = threadIdx.x, lane = tid & 63, wid = tid >> 6;
    const long row = (long)blockIdx.x * 4 + wid;
    const float* p = L + row * 512 + lane * 8;
    float v[8];
    *(float4*)&v[0] = *(const float4*)p;
    *(float4*)&v[4] = *(const float4*)(p + 4);
    float mx = v[0];
#pragma unroll
    for (int i = 1; i < 8; i++) mx = fmaxf(mx, v[i]);
    for (int d = 1; d < 64; d <<= 1) mx = fmaxf(mx, __shfl_xor(mx, d));
    float s = 0.f;
#pragma unroll
    for (int i = 0; i < 8; i++) { v[i] = __expf(v[i] - mx); s += v[i]; }
    for (int d = 1; d < 64; d <<= 1) s += __shfl_xor(s, d);
    float inv = 1.f / s;
    u16 o[8];
#pragma unroll
    for (int i = 0; i < 8; i++) o[i] = f2b(v[i] * inv);
    *(short8*)(Kout + row * 512 + lane * 8) = *(short8*)o;
}

// ---------------------------------------------------------------------------
// Fused flash attention over heads, 32 queries/block, direct-global B-frags.
//   out[n][o] = bf[o] + sum_h (1/l_h[n]) sum_m exp(kq[n].key_h[m]) * vpt[h][o][m]
// 512 threads (8 waves), QBLK=32 so LDS ~66 KB -> 2 blocks/CU (4 waves/SIMD)
// with __launch_bounds__(512,4) capping regs at 128 (acc tile = 64 regs, so
// ~60 arch VGPRs remain for in-flight loads -- round-1's 64-reg collapse fixed).
// l-reduction is race-free partial-sum array (no LDS atomics).
// ---------------------------------------------------------------------------
#define QB 32
#define LDQ 520     // row stride u16; 1040 B rows stay 16B-aligned (b128 fused),
#define LDP 520     // bank step 4 -> worst 2-way (free per m136)
#define FLASH_LDS (QB * LDQ * 2 + QB * LDP * 2 + 8 * 32 * 4 + 32 * 4)

__global__ __launch_bounds__(512, 4) void flash(
    const float* __restrict__ kq, const u16* __restrict__ key,
    const u16* __restrict__ vpt, const float* __restrict__ bfv, float* __restrict__ out)
{
    extern __shared__ u16 sm[];
    u16* kq_s = sm;                                  // [QB][LDQ]
    u16* Ph   = sm + QB * LDQ;                       // [QB][LDP]
    float* lpart = (float*)(sm + QB * (LDQ + LDP));  // [8 waves][32 rows]
    float* lfin  = lpart + 8 * 32;                   // [32]

    const int tid = threadIdx.x, lane = tid & 63, wid = tid >> 6;  // wid in [0,8)
    const int n0 = blockIdx.x * QB;
    const int rl = lane & 15, rq = (lane >> 4) * 4, gl8 = (lane >> 4) * 8;

    // stage Q tile [32][512] fp32 -> bf16 LDS
#pragma unroll
    for (int i = 0; i < 4; i++) {
        int c = tid + i * 512;                 // 2048 chunks of 8
        int r = c >> 6, cc = (c & 63) * 8;
        *(short8*)&kq_s[r * LDQ + cc] = cvt8(&kq[(long)(n0 + r) * 512 + cc]);
    }
    __syncthreads();

    floatx4 zero4 = {0.f, 0.f, 0.f, 0.f};
    floatx4 oacc[2][4], utmp[2][4];
#pragma unroll
    for (int i = 0; i < 2; i++)
#pragma unroll
        for (int j = 0; j < 4; j++) { oacc[i][j] = zero4; utmp[i][j] = zero4; }

    for (int h = 0; h < Hh; h++) {
        const u16* keyh = key + (long)h * Mm * Oo;
        const u16* vph = vpt + (long)h * Oo * Mm;

        for (int hf = 0; hf < 2; hf++) {
            // ---- S phase: Ph[q][m'] = exp(kq[q] . key_h[hf*512+m']) ----
            float psum[2][4];
#pragma unroll
            for (int qt = 0; qt < 2; qt++)
#pragma unroll
                for (int r = 0; r < 4; r++) psum[qt][r] = 0.f;

#pragma unroll
            for (int t = 0; t < 4; t++) {
                int mb = hf * 512 + wid * 64 + t * 16;   // this wave's 16 m-rows
                const u16* bp = keyh + (long)(mb + rl) * 512 + gl8;
                floatx4 s[2];
                s[0] = zero4; s[1] = zero4;
                __builtin_amdgcn_s_setprio(1);
#pragma unroll
                for (int ks = 0; ks < 16; ks++) {
                    short8 b = *(const short8*)(bp + ks * 32);
#pragma unroll
                    for (int qt = 0; qt < 2; qt++) {
                        short8 a = *(const short8*)&kq_s[(qt * 16 + rl) * LDQ + ks * 32 + gl8];
                        s[qt] = __builtin_amdgcn_mfma_f32_16x16x32_bf16(a, b, s[qt], 0, 0, 0);
                    }
                }
                __builtin_amdgcn_s_setprio(0);
                int colP = wid * 64 + t * 16 + rl;
#pragma unroll
                for (int qt = 0; qt < 2; qt++)
#pragma unroll
                    for (int r = 0; r < 4; r++) {
                        float e = __expf(s[qt][r]);   // |logit| <= max|kq| ~ 5.6
                        psum[qt][r] += e;
                        Ph[(qt * 16 + rq + r) * LDP + colP] = f2b(e);
                    }
            }
            // reduce across the 16-lane group (covers this wave's 64 m-cols)
            for (int d = 1; d < 16; d <<= 1)
#pragma unroll
                for (int qt = 0; qt < 2; qt++)
#pragma unroll
                    for (int r = 0; r < 4; r++) psum[qt][r] += __shfl_xor(psum[qt][r], d);
            if (rl == 0) {
#pragma unroll
                for (int qt = 0; qt < 2; qt++)
#pragma unroll
                    for (int r = 0; r < 4; r++) {
                        int row = qt * 16 + rq + r;
                        if (hf == 0) lpart[wid * 32 + row] = psum[qt][r];
                        else         lpart[wid * 32 + row] += psum[qt][r];
                    }
            }
            __syncthreads();

            // full row-sum once both halves are in (runs on 32 threads while
            // the rest start PV; consumed only after the post-PV barrier)
            if (hf == 1 && tid < 32) {
                float sum = 0.f;
#pragma unroll
                for (int w = 0; w < 8; w++) sum += lpart[w * 32 + tid];
                lfin[tid] = sum;
            }

            // ---- PV phase: utmp += Ph @ V'_h[:, hf-half]^T ----
            const u16* vbp[4];
#pragma unroll
            for (int ot = 0; ot < 4; ot++)
                vbp[ot] = vph + (long)(wid * 64 + ot * 16 + rl) * Mm + hf * 512 + gl8;
            __builtin_amdgcn_s_setprio(1);
#pragma unroll 4
            for (int mk = 0; mk < 16; mk++) {
                short8 a[2], b[4];
#pragma unroll
                for (int qt = 0; qt < 2; qt++)
                    a[qt] = *(const short8*)&Ph[(qt * 16 + rl) * LDP + mk * 32 + gl8];
#pragma unroll
                for (int ot = 0; ot < 4; ot++)
                    b[ot] = *(const short8*)(vbp[ot] + mk * 32);
#pragma unroll
                for (int qt = 0; qt < 2; qt++)
#pragma unroll
                    for (int ot = 0; ot < 4; ot++)
                        utmp[qt][ot] = __builtin_amdgcn_mfma_f32_16x16x32_bf16(a[qt], b[ot], utmp[qt][ot], 0, 0, 0);
            }
            __builtin_amdgcn_s_setprio(0);
            __syncthreads();   // Ph reads done; lfin visible

            if (hf == 1) {
                // scale per-head contribution by 1/l and fold into oacc
#pragma unroll
                for (int qt = 0; qt < 2; qt++)
#pragma unroll
                    for (int r = 0; r < 4; r++) {
                        float inv = 1.f / lfin[qt * 16 + rq + r];
#pragma unroll
                        for (int ot = 0; ot < 4; ot++) {
                            oacc[qt][ot][r] += inv * utmp[qt][ot][r];
                            utmp[qt][ot][r] = 0.f;
                        }
                    }
            }
        }
    }

    // epilogue: out[n][col] = oacc + bf[col]  (fp32 store)
#pragma unroll
    for (int qt = 0; qt < 2; qt++)
#pragma unroll
        for (int ot = 0; ot < 4; ot++) {
            int col = wid * 64 + ot * 16 + rl;
            float add = bfv[col];
#pragma unroll
            for (int r = 0; r < 4; r++) {
                int row = n0 + qt * 16 + rq + r;
                out[(long)row * 512 + col] = oacc[qt][ot][r] + add;
            }
        }
}

// ---------------------------------------------------------------------------
extern "C" void kernel_launch(void* const* d_in, const int* in_sizes, int n_in,
                              void* d_out, int out_size, void* d_ws, size_t ws_size,
                              hipStream_t stream)
{
    const float* k    = (const float*)d_in[0];   // [N][O] fp32
    const void*  mems = d_in[1];                 // [H][M][D] fp32
    const void*  Wk   = d_in[2];                 // [H][O][D] fp32
    const float* bk   = (const float*)d_in[3];   // [H][O] fp32
    const void*  Wv   = d_in[4];                 // [H][O][D] fp32
    const float* bv   = (const float*)d_in[5];   // [H][O] fp32
    const void*  Wf   = d_in[6];                 // [O][H*O] fp32
    const float* bfv  = (const float*)d_in[7];   // [O] fp32
    float* out = (float*)d_out;

    char* ws = (char*)d_ws;
    float* logits = (float*)ws;                                   // H*M*O fp32 = 32 MB
    u16* keyb = (u16*)(ws + (size_t)Hh * Mm * Oo * 4);            // H*M*O bf16 = 16 MB
    u16* valb = keyb + (size_t)Hh * Mm * Oo;                      // 16 MB
    u16* vptb = valb + (size_t)Hh * Mm * Oo;                      // V'^T [H][O][M], 16 MB

    // key logits: [h][m][o] = mems_h @ Wk_h^T + bk_h   (fp32 out)
    gemm_bt<<<dim3(8, 16, 16), 256, 0, stream>>>(
        mems, Wk, bk, logits, 512, 512, 512, 512,
        (long)Mm * Dd, (long)Oo * Dd, 512L, (long)Mm * Oo, 1, 1, 0);

    // mem_key = softmax(logits) -> bf16
    softmax_rows<<<dim3(Hh * Mm / 4), 256, 0, stream>>>(logits, keyb);

    // val: [h][m][o] = mems_h @ Wv_h^T + bv_h   (bf16 out)
    gemm_bt<<<dim3(8, 16, 16), 256, 0, stream>>>(
        mems, Wv, bv, valb, 512, 512, 512, 512,
        (long)Mm * Dd, (long)Oo * Dd, 512L, (long)Mm * Oo, 1, 1, 1);

    // V'^T: [h][o][m] = Wf[:, h*O:(h+1)*O] @ val_h^T   (bf16 out, transposed)
    gemm_bt<<<dim3(16, 8, 16), 256, 0, stream>>>(
        Wf, valb, nullptr, vptb, 512, Hh * Oo, 512, 1024,
        512L, (long)Mm * Oo, 0L, (long)Oo * Mm, 1, 0, 1);

    // fused attention over all heads, final projection pre-folded into V'
    flash<<<dim3(Nn / QB), 512, FLASH_LDS, stream>>>(k, keyb, vptb, bfv, out);
}

// Round 3
// 1791.348 us; speedup vs baseline: 1.1585x; 1.1585x over previous
//
#include <hip/hip_runtime.h>
#include <hip/hip_cooperative_groups.h>
#include <math.h>

namespace cg = cooperative_groups;

typedef unsigned short u16;
typedef __attribute__((ext_vector_type(8))) short short8;
typedef __attribute__((ext_vector_type(4))) float floatx4;

#define Hh 16
#define Mm 1024
#define Dd 512
#define Oo 512
#define Nn 16384

__device__ __forceinline__ float b2f(u16 u) { return __uint_as_float(((unsigned)u) << 16); }
__device__ __forceinline__ u16 f2b(float f) {
    unsigned v = __float_as_uint(f);
    v += 0x7fffu + ((v >> 16) & 1u);
    return (u16)(v >> 16);
}
__device__ __forceinline__ short8 cvt8(const float* p) {
    float4 a = *(const float4*)p, b = *(const float4*)(p + 4);
    u16 o[8];
    o[0] = f2b(a.x); o[1] = f2b(a.y); o[2] = f2b(a.z); o[3] = f2b(a.w);
    o[4] = f2b(b.x); o[5] = f2b(b.y); o[6] = f2b(b.z); o[7] = f2b(b.w);
    return *(short8*)o;
}

// ---------------------------------------------------------------------------
// Generic GEMM-BT: C[h][m][n] = sum_k A[h][m][k] * B[h][n][k] (+ bias[h][n])
// ---------------------------------------------------------------------------
__global__ __launch_bounds__(256) void gemm_bt(
    const void* __restrict__ A, const void* __restrict__ B, const float* __restrict__ bias,
    void* __restrict__ C, int K, int lda, int ldb, int ldc,
    long sA, long sB, long sBias, long sC, int aF32, int bF32, int outBf)
{
    __shared__ u16 At[64][72];
    __shared__ u16 Bt[64][72];
    const int tid = threadIdx.x, lane = tid & 63, wid = tid >> 6;
    const int m0 = blockIdx.y * 64, n0 = blockIdx.x * 64;
    const int h = blockIdx.z;
    const int wm = wid >> 1, wn = wid & 1;
    const int rl = lane & 15, rq = (lane >> 4) * 4, gl8 = (lane >> 4) * 8;

    floatx4 zero4 = {0.f, 0.f, 0.f, 0.f};
    floatx4 acc[2][2];
    acc[0][0] = zero4; acc[0][1] = zero4; acc[1][0] = zero4; acc[1][1] = zero4;

    for (int k0 = 0; k0 < K; k0 += 64) {
#pragma unroll
        for (int i = 0; i < 2; i++) {
            int c = tid + i * 256;
            int r = c >> 3, cc = (c & 7) * 8;
            long aoff = (long)h * sA + (long)(m0 + r) * lda + k0 + cc;
            long boff = (long)h * sB + (long)(n0 + r) * ldb + k0 + cc;
            *(short8*)&At[r][cc] = aF32 ? cvt8((const float*)A + aoff)
                                        : *(const short8*)((const u16*)A + aoff);
            *(short8*)&Bt[r][cc] = bF32 ? cvt8((const float*)B + boff)
                                        : *(const short8*)((const u16*)B + boff);
        }
        __syncthreads();
#pragma unroll
        for (int ks = 0; ks < 2; ks++) {
            short8 a0 = *(const short8*)&At[wm * 32 + rl][ks * 32 + gl8];
            short8 a1 = *(const short8*)&At[wm * 32 + 16 + rl][ks * 32 + gl8];
            short8 b0 = *(const short8*)&Bt[wn * 32 + rl][ks * 32 + gl8];
            short8 b1 = *(const short8*)&Bt[wn * 32 + 16 + rl][ks * 32 + gl8];
            acc[0][0] = __builtin_amdgcn_mfma_f32_16x16x32_bf16(a0, b0, acc[0][0], 0, 0, 0);
            acc[0][1] = __builtin_amdgcn_mfma_f32_16x16x32_bf16(a0, b1, acc[0][1], 0, 0, 0);
            acc[1][0] = __builtin_amdgcn_mfma_f32_16x16x32_bf16(a1, b0, acc[1][0], 0, 0, 0);
            acc[1][1] = __builtin_amdgcn_mfma_f32_16x16x32_bf16(a1, b1, acc[1][1], 0, 0, 0);
        }
        __syncthreads();
    }

#pragma unroll
    for (int i = 0; i < 2; i++)
#pragma unroll
        for (int j = 0; j < 2; j++) {
            int col = n0 + wn * 32 + j * 16 + rl;
            float bb = bias ? bias[(long)h * sBias + col] : 0.f;
#pragma unroll
            for (int r = 0; r < 4; r++) {
                int row = m0 + wm * 32 + i * 16 + rq + r;
                long idx = (long)h * sC + (long)row * ldc + col;
                float v = acc[i][j][r] + bb;
                if (outBf) ((u16*)C)[idx] = f2b(v);
                else       ((float*)C)[idx] = v;
            }
        }
}

// ---------------------------------------------------------------------------
// Row softmax: rows of 512 fp32 logits -> bf16 probabilities. One wave/row.
// ---------------------------------------------------------------------------
__global__ __launch_bounds__(256) void softmax_rows(const float* __restrict__ L, u16* __restrict__ Kout)
{
    const int tid = threadIdx.x, lane = tid & 63, wid = tid >> 6;
    const long row = (long)blockIdx.x * 4 + wid;
    const float* p = L + row * 512 + lane * 8;
    float v[8];
    *(float4*)&v[0] = *(const float4*)p;
    *(float4*)&v[4] = *(const float4*)(p + 4);
    float mx = v[0];
#pragma unroll
    for (int i = 1; i < 8; i++) mx = fmaxf(mx, v[i]);
    for (int d = 1; d < 64; d <<= 1) mx = fmaxf(mx, __shfl_xor(mx, d));
    float s = 0.f;
#pragma unroll
    for (int i = 0; i < 8; i++) { v[i] = __expf(v[i] - mx); s += v[i]; }
    for (int d = 1; d < 64; d <<= 1) s += __shfl_xor(s, d);
    float inv = 1.f / s;
    u16 o[8];
#pragma unroll
    for (int i = 0; i < 8; i++) o[i] = f2b(v[i] * inv);
    *(short8*)(Kout + row * 512 + lane * 8) = *(short8*)o;
}

// ---------------------------------------------------------------------------
// Fused flash attention over heads, 64 queries/block, direct-global B-frags.
//   out[n][o] = bf[o] + sum_h (1/l_h[n]) sum_m exp(kq[n].key_h[m]) * vpt[h][o][m]
// Round-0 structure (512 thr, 8 waves, 1 block/CU, 2 waves/SIMD, 256-reg
// budget -> acc 128 + ~104 arch, no register collapse).
// NEW: cooperative launch + grid.sync() per head. All 256 blocks stream the
// SAME key/vpt bytes; syncing per head bounds cross-block drift to the head's
// 2 MB working set (< 4 MB per-XCD L2), so the 32 blocks/XCD re-read each
// head from L2 (34.5 TB/s aggregate) instead of L3.
// Also: race-free lpart row-sum (replaces LDS atomicAdd serialization).
// ---------------------------------------------------------------------------
#define LDQ 520     // Q row stride u16 (1040B rows stay 16B-aligned for b128)
#define LDP 520
#define FLASH_LDS ((64 * LDQ + 64 * LDP) * 2 + 8 * 64 * 4 + 64 * 4)

__global__ __launch_bounds__(512, 2) void flash(
    const float* __restrict__ kq, const u16* __restrict__ key,
    const u16* __restrict__ vpt, const float* __restrict__ bfv, float* __restrict__ out)
{
    cg::grid_group grid = cg::this_grid();
    extern __shared__ u16 sm[];
    u16* kq_s = sm;                                  // [64][LDQ]
    u16* Ph   = sm + 64 * LDQ;                       // [64][LDP]
    float* lpart = (float*)(sm + 64 * (LDQ + LDP));  // [8 waves][64 rows]
    float* lfin  = lpart + 8 * 64;                   // [64]

    const int tid = threadIdx.x, lane = tid & 63, wid = tid >> 6;  // wid in [0,8)
    const int n0 = blockIdx.x * 64;
    const int rl = lane & 15, rq = (lane >> 4) * 4, gl8 = (lane >> 4) * 8;

    // load+convert query tile [64][512] fp32 -> bf16 LDS
#pragma unroll
    for (int i = 0; i < 8; i++) {
        int c = tid + i * 512;                 // 4096 chunks of 8
        int r = c >> 6, cc = (c & 63) * 8;
        *(short8*)&kq_s[r * LDQ + cc] = cvt8(&kq[(long)(n0 + r) * 512 + cc]);
    }
    __syncthreads();

    floatx4 zero4 = {0.f, 0.f, 0.f, 0.f};
    floatx4 oacc[4][4], utmp[4][4];
#pragma unroll
    for (int i = 0; i < 4; i++)
#pragma unroll
        for (int j = 0; j < 4; j++) { oacc[i][j] = zero4; utmp[i][j] = zero4; }

    for (int h = 0; h < Hh; h++) {
        const u16* keyh = key + (long)h * Mm * Oo;
        const u16* vph = vpt + (long)h * Oo * Mm;

        for (int hf = 0; hf < 2; hf++) {
            // ---- S phase: Ph[q][m'] = exp(kq[q] . key_h[hf*512+m']) ----
            float psum[4][4];
#pragma unroll
            for (int qt = 0; qt < 4; qt++)
#pragma unroll
                for (int r = 0; r < 4; r++) psum[qt][r] = 0.f;

            for (int t = 0; t < 4; t++) {
                int mb = hf * 512 + wid * 64 + t * 16;   // this wave's 16 m-rows
                const u16* bp = keyh + (long)(mb + rl) * 512 + gl8;
                floatx4 s[4];
#pragma unroll
                for (int qt = 0; qt < 4; qt++) s[qt] = zero4;
#pragma unroll
                for (int ks = 0; ks < 16; ks++) {
                    short8 b = *(const short8*)(bp + ks * 32);
#pragma unroll
                    for (int qt = 0; qt < 4; qt++) {
                        short8 a = *(const short8*)&kq_s[(qt * 16 + rl) * LDQ + ks * 32 + gl8];
                        s[qt] = __builtin_amdgcn_mfma_f32_16x16x32_bf16(a, b, s[qt], 0, 0, 0);
                    }
                }
                int colP = wid * 64 + t * 16 + rl;
#pragma unroll
                for (int qt = 0; qt < 4; qt++)
#pragma unroll
                    for (int r = 0; r < 4; r++) {
                        float e = __expf(s[qt][r]);   // |logit| <= max|kq| ~ 5.6
                        psum[qt][r] += e;
                        Ph[(qt * 16 + rq + r) * LDP + colP] = f2b(e);
                    }
            }
            // wave-level row-sum (over this wave's 64 m), race-free partials
            for (int d = 1; d < 16; d <<= 1)
#pragma unroll
                for (int qt = 0; qt < 4; qt++)
#pragma unroll
                    for (int r = 0; r < 4; r++) psum[qt][r] += __shfl_xor(psum[qt][r], d);
            if (rl == 0) {
#pragma unroll
                for (int qt = 0; qt < 4; qt++)
#pragma unroll
                    for (int r = 0; r < 4; r++) {
                        int row = qt * 16 + rq + r;
                        if (hf == 0) lpart[wid * 64 + row] = psum[qt][r];
                        else         lpart[wid * 64 + row] += psum[qt][r];
                    }
            }
            __syncthreads();

            // final row-sum once both halves are in (64 threads, overlaps PV;
            // consumed only after the post-PV barrier)
            if (hf == 1 && tid < 64) {
                float sum = 0.f;
#pragma unroll
                for (int w = 0; w < 8; w++) sum += lpart[w * 64 + tid];
                lfin[tid] = sum;
            }

            // ---- PV phase: utmp += Ph @ V'_h[:, hf-half]^T ----
            const u16* vbp[4];
#pragma unroll
            for (int ot = 0; ot < 4; ot++)
                vbp[ot] = vph + (long)(wid * 64 + ot * 16 + rl) * Mm + hf * 512 + gl8;
#pragma unroll 4
            for (int mk = 0; mk < 16; mk++) {
                short8 a[4], b[4];
#pragma unroll
                for (int qt = 0; qt < 4; qt++)
                    a[qt] = *(const short8*)&Ph[(qt * 16 + rl) * LDP + mk * 32 + gl8];
#pragma unroll
                for (int ot = 0; ot < 4; ot++)
                    b[ot] = *(const short8*)(vbp[ot] + mk * 32);
#pragma unroll
                for (int qt = 0; qt < 4; qt++)
#pragma unroll
                    for (int ot = 0; ot < 4; ot++)
                        utmp[qt][ot] = __builtin_amdgcn_mfma_f32_16x16x32_bf16(a[qt], b[ot], utmp[qt][ot], 0, 0, 0);
            }
            __syncthreads();   // Ph reads done before next S overwrites; lfin visible

            if (hf == 1) {
                // scale per-head contribution by 1/l and fold into oacc
#pragma unroll
                for (int qt = 0; qt < 4; qt++)
#pragma unroll
                    for (int r = 0; r < 4; r++) {
                        float inv = 1.f / lfin[qt * 16 + rq + r];
#pragma unroll
                        for (int ot = 0; ot < 4; ot++) {
                            oacc[qt][ot][r] += inv * utmp[qt][ot][r];
                            utmp[qt][ot][r] = 0.f;
                        }
                    }
            }
        }

        // re-align all 256 blocks so the per-XCD L2 serves the shared stream
        if (h < Hh - 1) grid.sync();
    }

    // epilogue: out[n][col] = oacc + bf[col]  (fp32 store)
#pragma unroll
    for (int qt = 0; qt < 4; qt++)
#pragma unroll
        for (int ot = 0; ot < 4; ot++) {
            int col = wid * 64 + ot * 16 + rl;
            float add = bfv[col];
#pragma unroll
            for (int r = 0; r < 4; r++) {
                int row = n0 + qt * 16 + rq + r;
                out[(long)row * 512 + col] = oacc[qt][ot][r] + add;
            }
        }
}

// ---------------------------------------------------------------------------
extern "C" void kernel_launch(void* const* d_in, const int* in_sizes, int n_in,
                              void* d_out, int out_size, void* d_ws, size_t ws_size,
                              hipStream_t stream)
{
    const float* k    = (const float*)d_in[0];   // [N][O] fp32
    const void*  mems = d_in[1];                 // [H][M][D] fp32
    const void*  Wk   = d_in[2];                 // [H][O][D] fp32
    const float* bk   = (const float*)d_in[3];   // [H][O] fp32
    const void*  Wv   = d_in[4];                 // [H][O][D] fp32
    const float* bv   = (const float*)d_in[5];   // [H][O] fp32
    const void*  Wf   = d_in[6];                 // [O][H*O] fp32
    const float* bfv  = (const float*)d_in[7];   // [O] fp32
    float* out = (float*)d_out;

    char* ws = (char*)d_ws;
    float* logits = (float*)ws;                                   // H*M*O fp32 = 32 MB
    u16* keyb = (u16*)(ws + (size_t)Hh * Mm * Oo * 4);            // H*M*O bf16 = 16 MB
    u16* valb = keyb + (size_t)Hh * Mm * Oo;                      // 16 MB
    u16* vptb = valb + (size_t)Hh * Mm * Oo;                      // V'^T [H][O][M], 16 MB

    // key logits: [h][m][o] = mems_h @ Wk_h^T + bk_h   (fp32 out)
    gemm_bt<<<dim3(8, 16, 16), 256, 0, stream>>>(
        mems, Wk, bk, logits, 512, 512, 512, 512,
        (long)Mm * Dd, (long)Oo * Dd, 512L, (long)Mm * Oo, 1, 1, 0);

    // mem_key = softmax(logits) -> bf16
    softmax_rows<<<dim3(Hh * Mm / 4), 256, 0, stream>>>(logits, keyb);

    // val: [h][m][o] = mems_h @ Wv_h^T + bv_h   (bf16 out)
    gemm_bt<<<dim3(8, 16, 16), 256, 0, stream>>>(
        mems, Wv, bv, valb, 512, 512, 512, 512,
        (long)Mm * Dd, (long)Oo * Dd, 512L, (long)Mm * Oo, 1, 1, 1);

    // V'^T: [h][o][m] = Wf[:, h*O:(h+1)*O] @ val_h^T   (bf16 out, transposed)
    gemm_bt<<<dim3(16, 8, 16), 256, 0, stream>>>(
        Wf, valb, nullptr, vptb, 512, Hh * Oo, 512, 1024,
        512L, (long)Mm * Oo, 0L, (long)Oo * Mm, 1, 0, 1);

    // fused attention over all heads, final projection pre-folded into V'.
    // Cooperative launch: grid=256 blocks (1/CU guaranteed co-resident) so
    // the per-head grid.sync() keeps all blocks' streams phase-aligned.
    void* kargs[] = { (void*)&k, (void*)&keyb, (void*)&vptb, (void*)&bfv, (void*)&out };
    hipLaunchCooperativeKernel((void*)flash, dim3(Nn / 64), dim3(512),
                               kargs, (unsigned)FLASH_LDS, stream);
}

// Round 4
// 1527.171 us; speedup vs baseline: 1.3589x; 1.1730x over previous
//
#include <hip/hip_runtime.h>
#include <math.h>

typedef unsigned short u16;
typedef __attribute__((ext_vector_type(8))) short short8;
typedef __attribute__((ext_vector_type(4))) float floatx4;

#define Hh 16
#define Mm 1024
#define Dd 512
#define Oo 512
#define Nn 16384

__device__ __forceinline__ float b2f(u16 u) { return __uint_as_float(((unsigned)u) << 16); }
__device__ __forceinline__ u16 f2b(float f) {
    unsigned v = __float_as_uint(f);
    v += 0x7fffu + ((v >> 16) & 1u);
    return (u16)(v >> 16);
}
__device__ __forceinline__ short8 cvt8(const float* p) {
    float4 a = *(const float4*)p, b = *(const float4*)(p + 4);
    u16 o[8];
    o[0] = f2b(a.x); o[1] = f2b(a.y); o[2] = f2b(a.z); o[3] = f2b(a.w);
    o[4] = f2b(b.x); o[5] = f2b(b.y); o[6] = f2b(b.z); o[7] = f2b(b.w);
    return *(short8*)o;
}

// ---------------------------------------------------------------------------
// Generic GEMM-BT: C[h][m][n] = sum_k A[h][m][k] * B[h][n][k] (+ bias[h][n])
// ---------------------------------------------------------------------------
__global__ __launch_bounds__(256) void gemm_bt(
    const void* __restrict__ A, const void* __restrict__ B, const float* __restrict__ bias,
    void* __restrict__ C, int K, int lda, int ldb, int ldc,
    long sA, long sB, long sBias, long sC, int aF32, int bF32, int outBf)
{
    __shared__ u16 At[64][72];
    __shared__ u16 Bt[64][72];
    const int tid = threadIdx.x, lane = tid & 63, wid = tid >> 6;
    const int m0 = blockIdx.y * 64, n0 = blockIdx.x * 64;
    const int h = blockIdx.z;
    const int wm = wid >> 1, wn = wid & 1;
    const int rl = lane & 15, rq = (lane >> 4) * 4, gl8 = (lane >> 4) * 8;

    floatx4 zero4 = {0.f, 0.f, 0.f, 0.f};
    floatx4 acc[2][2];
    acc[0][0] = zero4; acc[0][1] = zero4; acc[1][0] = zero4; acc[1][1] = zero4;

    for (int k0 = 0; k0 < K; k0 += 64) {
#pragma unroll
        for (int i = 0; i < 2; i++) {
            int c = tid + i * 256;
            int r = c >> 3, cc = (c & 7) * 8;
            long aoff = (long)h * sA + (long)(m0 + r) * lda + k0 + cc;
            long boff = (long)h * sB + (long)(n0 + r) * ldb + k0 + cc;
            *(short8*)&At[r][cc] = aF32 ? cvt8((const float*)A + aoff)
                                        : *(const short8*)((const u16*)A + aoff);
            *(short8*)&Bt[r][cc] = bF32 ? cvt8((const float*)B + boff)
                                        : *(const short8*)((const u16*)B + boff);
        }
        __syncthreads();
#pragma unroll
        for (int ks = 0; ks < 2; ks++) {
            short8 a0 = *(const short8*)&At[wm * 32 + rl][ks * 32 + gl8];
            short8 a1 = *(const short8*)&At[wm * 32 + 16 + rl][ks * 32 + gl8];
            short8 b0 = *(const short8*)&Bt[wn * 32 + rl][ks * 32 + gl8];
            short8 b1 = *(const short8*)&Bt[wn * 32 + 16 + rl][ks * 32 + gl8];
            acc[0][0] = __builtin_amdgcn_mfma_f32_16x16x32_bf16(a0, b0, acc[0][0], 0, 0, 0);
            acc[0][1] = __builtin_amdgcn_mfma_f32_16x16x32_bf16(a0, b1, acc[0][1], 0, 0, 0);
            acc[1][0] = __builtin_amdgcn_mfma_f32_16x16x32_bf16(a1, b0, acc[1][0], 0, 0, 0);
            acc[1][1] = __builtin_amdgcn_mfma_f32_16x16x32_bf16(a1, b1, acc[1][1], 0, 0, 0);
        }
        __syncthreads();
    }

#pragma unroll
    for (int i = 0; i < 2; i++)
#pragma unroll
        for (int j = 0; j < 2; j++) {
            int col = n0 + wn * 32 + j * 16 + rl;
            float bb = bias ? bias[(long)h * sBias + col] : 0.f;
#pragma unroll
            for (int r = 0; r < 4; r++) {
                int row = m0 + wm * 32 + i * 16 + rq + r;
                long idx = (long)h * sC + (long)row * ldc + col;
                float v = acc[i][j][r] + bb;
                if (outBf) ((u16*)C)[idx] = f2b(v);
                else       ((float*)C)[idx] = v;
            }
        }
}

// ---------------------------------------------------------------------------
// Row softmax: rows of 512 fp32 logits -> bf16 probabilities. One wave/row.
// ---------------------------------------------------------------------------
__global__ __launch_bounds__(256) void softmax_rows(const float* __restrict__ L, u16* __restrict__ Kout)
{
    const int tid = threadIdx.x, lane = tid & 63, wid = tid >> 6;
    const long row = (long)blockIdx.x * 4 + wid;
    const float* p = L + row * 512 + lane * 8;
    float v[8];
    *(float4*)&v[0] = *(const float4*)p;
    *(float4*)&v[4] = *(const float4*)(p + 4);
    float mx = v[0];
#pragma unroll
    for (int i = 1; i < 8; i++) mx = fmaxf(mx, v[i]);
    for (int d = 1; d < 64; d <<= 1) mx = fmaxf(mx, __shfl_xor(mx, d));
    float s = 0.f;
#pragma unroll
    for (int i = 0; i < 8; i++) { v[i] = __expf(v[i] - mx); s += v[i]; }
    for (int d = 1; d < 64; d <<= 1) s += __shfl_xor(s, d);
    float inv = 1.f / s;
    u16 o[8];
#pragma unroll
    for (int i = 0; i < 8; i++) o[i] = f2b(v[i] * inv);
    *(short8*)(Kout + row * 512 + lane * 8) = *(short8*)o;
}

// ---------------------------------------------------------------------------
// Fused flash attention over heads, 64 queries/block, direct-global B-frags.
//   out[n][o] = bf[o] + sum_h (1/l_h[n]) sum_m exp(kq[n].key_h[m]) * vpt[h][o][m]
// Round-0 structure (512 thr, 8 waves, 1 block/CU). NEW this round:
//  - S phase processes m-tiles in PAIRS with two interleaved load streams:
//    32 independent key-loads visible per wave (vs 16), halving the number of
//    serializing exp/store tails per byte and halving Q LDS fragment reads.
//    Little's law said round-0 kept only ~6 loads in flight per CU; this is
//    the direct MLP fix.
//  - P row-XOR swizzle (col ^= ((row>>2)&3)<<4): rows {r,4+r,8+r,12+r} no
//    longer alias pairwise on the scalar P-stores (was 4-way).
//  - race-free lpart row-sum (validated rounds 2/3), no LDS atomics.
// ---------------------------------------------------------------------------
#define LDQ 520     // Q row stride u16 (1040B rows stay 16B-aligned for b128)
#define LDP 520
#define FLASH_LDS ((64 * LDQ + 64 * LDP) * 2 + 8 * 64 * 4 + 64 * 4)

__global__ __launch_bounds__(512, 2) void flash(
    const float* __restrict__ kq, const u16* __restrict__ key,
    const u16* __restrict__ vpt, const float* __restrict__ bfv, float* __restrict__ out)
{
    extern __shared__ u16 sm[];
    u16* kq_s = sm;                                  // [64][LDQ]
    u16* Ph   = sm + 64 * LDQ;                       // [64][LDP], col-swizzled
    float* lpart = (float*)(sm + 64 * (LDQ + LDP));  // [8 waves][64 rows]
    float* lfin  = lpart + 8 * 64;                   // [64]

    const int tid = threadIdx.x, lane = tid & 63, wid = tid >> 6;  // wid in [0,8)
    const int n0 = blockIdx.x * 64;
    const int rl = lane & 15, rq = (lane >> 4) * 4, gl8 = (lane >> 4) * 8;
    const int swzr = ((rl >> 2) & 3) << 4;           // P read-side swizzle

    // load+convert query tile [64][512] fp32 -> bf16 LDS
#pragma unroll
    for (int i = 0; i < 8; i++) {
        int c = tid + i * 512;                 // 4096 chunks of 8
        int r = c >> 6, cc = (c & 63) * 8;
        *(short8*)&kq_s[r * LDQ + cc] = cvt8(&kq[(long)(n0 + r) * 512 + cc]);
    }
    __syncthreads();

    floatx4 zero4 = {0.f, 0.f, 0.f, 0.f};
    floatx4 oacc[4][4], utmp[4][4];
#pragma unroll
    for (int i = 0; i < 4; i++)
#pragma unroll
        for (int j = 0; j < 4; j++) { oacc[i][j] = zero4; utmp[i][j] = zero4; }

    for (int h = 0; h < Hh; h++) {
        const u16* keyh = key + (long)h * Mm * Oo;
        const u16* vph = vpt + (long)h * Oo * Mm;

        for (int hf = 0; hf < 2; hf++) {
            // ---- S phase: Ph[q][m'] = exp(kq[q] . key_h[hf*512+m']) ----
            float psum[4][4];
#pragma unroll
            for (int qt = 0; qt < 4; qt++)
#pragma unroll
                for (int r = 0; r < 4; r++) psum[qt][r] = 0.f;

            for (int tp = 0; tp < 2; tp++) {
                // two independent 16-row m-streams, shared Q fragments
                int mb0 = hf * 512 + wid * 64 + tp * 32;
                const u16* bp0 = keyh + (long)(mb0 + rl) * 512 + gl8;
                const u16* bp1 = bp0 + 16 * 512;
                floatx4 s0[4], s1[4];
#pragma unroll
                for (int qt = 0; qt < 4; qt++) { s0[qt] = zero4; s1[qt] = zero4; }
#pragma unroll
                for (int ks = 0; ks < 16; ks++) {
                    short8 b0 = *(const short8*)(bp0 + ks * 32);
                    short8 b1 = *(const short8*)(bp1 + ks * 32);
#pragma unroll
                    for (int qt = 0; qt < 4; qt++) {
                        short8 a = *(const short8*)&kq_s[(qt * 16 + rl) * LDQ + ks * 32 + gl8];
                        s0[qt] = __builtin_amdgcn_mfma_f32_16x16x32_bf16(a, b0, s0[qt], 0, 0, 0);
                        s1[qt] = __builtin_amdgcn_mfma_f32_16x16x32_bf16(a, b1, s1[qt], 0, 0, 0);
                    }
                }
                int colP0 = wid * 64 + tp * 32 + rl;   // stream 0 cols; stream 1 at +16
#pragma unroll
                for (int qt = 0; qt < 4; qt++)
#pragma unroll
                    for (int r = 0; r < 4; r++) {
                        int row = qt * 16 + rq + r;
                        int swz = ((row >> 2) & 3) << 4;
                        float e0 = __expf(s0[qt][r]);  // |logit| <= max|kq| ~ 5.6
                        float e1 = __expf(s1[qt][r]);
                        psum[qt][r] += e0 + e1;
                        Ph[row * LDP + (colP0 ^ swz)] = f2b(e0);
                        Ph[row * LDP + ((colP0 + 16) ^ swz)] = f2b(e1);
                    }
            }
            // wave-level row-sum (over this wave's 64 m), race-free partials
            for (int d = 1; d < 16; d <<= 1)
#pragma unroll
                for (int qt = 0; qt < 4; qt++)
#pragma unroll
                    for (int r = 0; r < 4; r++) psum[qt][r] += __shfl_xor(psum[qt][r], d);
            if (rl == 0) {
#pragma unroll
                for (int qt = 0; qt < 4; qt++)
#pragma unroll
                    for (int r = 0; r < 4; r++) {
                        int row = qt * 16 + rq + r;
                        if (hf == 0) lpart[wid * 64 + row] = psum[qt][r];
                        else         lpart[wid * 64 + row] += psum[qt][r];
                    }
            }
            __syncthreads();

            // final row-sum once both halves are in (64 threads, overlaps PV;
            // consumed only after the post-PV barrier)
            if (hf == 1 && tid < 64) {
                float sum = 0.f;
#pragma unroll
                for (int w = 0; w < 8; w++) sum += lpart[w * 64 + tid];
                lfin[tid] = sum;
            }

            // ---- PV phase: utmp += Ph @ V'_h[:, hf-half]^T ----
            const u16* vbp[4];
#pragma unroll
            for (int ot = 0; ot < 4; ot++)
                vbp[ot] = vph + (long)(wid * 64 + ot * 16 + rl) * Mm + hf * 512 + gl8;
#pragma unroll 4
            for (int mk = 0; mk < 16; mk++) {
                short8 a[4], b[4];
#pragma unroll
                for (int qt = 0; qt < 4; qt++)
                    a[qt] = *(const short8*)&Ph[(qt * 16 + rl) * LDP + ((mk * 32 + gl8) ^ swzr)];
#pragma unroll
                for (int ot = 0; ot < 4; ot++)
                    b[ot] = *(const short8*)(vbp[ot] + mk * 32);
#pragma unroll
                for (int qt = 0; qt < 4; qt++)
#pragma unroll
                    for (int ot = 0; ot < 4; ot++)
                        utmp[qt][ot] = __builtin_amdgcn_mfma_f32_16x16x32_bf16(a[qt], b[ot], utmp[qt][ot], 0, 0, 0);
            }
            __syncthreads();   // Ph reads done before next S overwrites; lfin visible

            if (hf == 1) {
                // scale per-head contribution by 1/l and fold into oacc
#pragma unroll
                for (int qt = 0; qt < 4; qt++)
#pragma unroll
                    for (int r = 0; r < 4; r++) {
                        float inv = 1.f / lfin[qt * 16 + rq + r];
#pragma unroll
                        for (int ot = 0; ot < 4; ot++) {
                            oacc[qt][ot][r] += inv * utmp[qt][ot][r];
                            utmp[qt][ot][r] = 0.f;
                        }
                    }
            }
        }
    }

    // epilogue: out[n][col] = oacc + bf[col]  (fp32 store)
#pragma unroll
    for (int qt = 0; qt < 4; qt++)
#pragma unroll
        for (int ot = 0; ot < 4; ot++) {
            int col = wid * 64 + ot * 16 + rl;
            float add = bfv[col];
#pragma unroll
            for (int r = 0; r < 4; r++) {
                int row = n0 + qt * 16 + rq + r;
                out[(long)row * 512 + col] = oacc[qt][ot][r] + add;
            }
        }
}

// ---------------------------------------------------------------------------
extern "C" void kernel_launch(void* const* d_in, const int* in_sizes, int n_in,
                              void* d_out, int out_size, void* d_ws, size_t ws_size,
                              hipStream_t stream)
{
    const float* k    = (const float*)d_in[0];   // [N][O] fp32
    const void*  mems = d_in[1];                 // [H][M][D] fp32
    const void*  Wk   = d_in[2];                 // [H][O][D] fp32
    const float* bk   = (const float*)d_in[3];   // [H][O] fp32
    const void*  Wv   = d_in[4];                 // [H][O][D] fp32
    const float* bv   = (const float*)d_in[5];   // [H][O] fp32
    const void*  Wf   = d_in[6];                 // [O][H*O] fp32
    const float* bfv  = (const float*)d_in[7];   // [O] fp32
    float* out = (float*)d_out;

    char* ws = (char*)d_ws;
    float* logits = (float*)ws;                                   // H*M*O fp32 = 32 MB
    u16* keyb = (u16*)(ws + (size_t)Hh * Mm * Oo * 4);            // H*M*O bf16 = 16 MB
    u16* valb = keyb + (size_t)Hh * Mm * Oo;                      // 16 MB
    u16* vptb = valb + (size_t)Hh * Mm * Oo;                      // V'^T [H][O][M], 16 MB

    // key logits: [h][m][o] = mems_h @ Wk_h^T + bk_h   (fp32 out)
    gemm_bt<<<dim3(8, 16, 16), 256, 0, stream>>>(
        mems, Wk, bk, logits, 512, 512, 512, 512,
        (long)Mm * Dd, (long)Oo * Dd, 512L, (long)Mm * Oo, 1, 1, 0);

    // mem_key = softmax(logits) -> bf16
    softmax_rows<<<dim3(Hh * Mm / 4), 256, 0, stream>>>(logits, keyb);

    // val: [h][m][o] = mems_h @ Wv_h^T + bv_h   (bf16 out)
    gemm_bt<<<dim3(8, 16, 16), 256, 0, stream>>>(
        mems, Wv, bv, valb, 512, 512, 512, 512,
        (long)Mm * Dd, (long)Oo * Dd, 512L, (long)Mm * Oo, 1, 1, 1);

    // V'^T: [h][o][m] = Wf[:, h*O:(h+1)*O] @ val_h^T   (bf16 out, transposed)
    gemm_bt<<<dim3(16, 8, 16), 256, 0, stream>>>(
        Wf, valb, nullptr, vptb, 512, Hh * Oo, 512, 1024,
        512L, (long)Mm * Oo, 0L, (long)Oo * Mm, 1, 0, 1);

    // fused attention over all heads, final projection pre-folded into V'
    flash<<<dim3(Nn / 64), 512, FLASH_LDS, stream>>>(k, keyb, vptb, bfv, out);
}